// Round 7
// baseline (268.730 us; speedup 1.0000x reference)
//
#include <hip/hip_runtime.h>
#include <hip/hip_bf16.h>
#include <stdint.h>

// Problem: B=64, N=32, D=512, P=992 pairs, M = B*P = 63488.
// out[m,d] = relu(U[i(m)] + V[j(m)])·W2[d,:] + b2[d]
// U = pf @ W1[:,:512]^T (+b1), V = pf @ W1[:,512:]^T   (only 2048 distinct rows)

typedef __attribute__((ext_vector_type(4))) float f32x4;
typedef __attribute__((ext_vector_type(8))) short bf16x8;
typedef __attribute__((ext_vector_type(4))) unsigned int u32x4;
typedef __attribute__((ext_vector_type(2))) unsigned int u32x2;

__device__ __forceinline__ uint32_t cvt2_bf16(float a, float b) {
    __hip_bfloat162 h = __float22bfloat162_rn(make_float2(a, b));
    uint32_t u;
    __builtin_memcpy(&u, &h, 4);
    return u;
}

__device__ __forceinline__ void async_lds16(const void* g, void* l) {
    __builtin_amdgcn_global_load_lds(
        (const __attribute__((address_space(1))) void*)g,
        (__attribute__((address_space(3))) void*)l, 16, 0, 0);
}

// ---------------------------------------------------------------------------
// Kernel 1 (merged): blocks 0..255 -> uv_gemm tile; blocks 256..383 ->
// W2 rearrange (32768 16B slots) into per-(step,col-half) chunked frag order:
//   slot s: l = s&63, fn = (s>>6)&15, ch = (s>>10)&1, kt = s>>11
//   col = ch*256 + fn*16 + (l&15), k = kt*32 + (l>>4)*8
// -> chunk (kt,ch) is a contiguous 16 KB block (the per-step DMA unit).
// ---------------------------------------------------------------------------
__global__ __launch_bounds__(256) void prep(const float* __restrict__ pf,
                                            const float* __restrict__ W1,
                                            const float* __restrict__ b1,
                                            const float* __restrict__ W2,
                                            float* __restrict__ UV,
                                            unsigned short* __restrict__ W2r) {
    __shared__ unsigned short As[64][64];
    __shared__ unsigned short Bs[128][64];

    const int t = threadIdx.x;
    const int bxg = blockIdx.x;

    if (bxg >= 256) {
        int s = (bxg - 256) * 256 + t;           // 0..32767
        int l = s & 63;
        int fn = (s >> 6) & 15;
        int ch = (s >> 10) & 1;
        int kt = s >> 11;
        int col = ch * 256 + fn * 16 + (l & 15);
        int k = kt * 32 + (l >> 4) * 8;
        const float* src = W2 + (size_t)col * 512 + k;
        f32x4 a = ((const f32x4*)src)[0];
        f32x4 b = ((const f32x4*)src)[1];
        u32x4 P;
        P[0] = cvt2_bf16(a[0], a[1]); P[1] = cvt2_bf16(a[2], a[3]);
        P[2] = cvt2_bf16(b[0], b[1]); P[3] = cvt2_bf16(b[2], b[3]);
        *(u32x4*)(W2r + (size_t)s * 8) = P;
        return;
    }

    // ---- uv_gemm: 64x128 tile, BK=64, 4 waves, XOR-swizzled LDS
    const int m0 = (bxg >> 3) * 64;
    const int c0 = (bxg & 7) * 128;

    const int sr = t >> 2;
    const int sk = (t & 3) << 4;
    const int g0 = (t & 3) << 1;

    const int wave = t >> 6, lane = t & 63;
    const int wr = wave >> 1, wc = wave & 1;
    const int lr = lane & 15, lkq = lane >> 4;
    const int s7 = lr & 7;

    f32x4 acc[2][4] = {};

    const float* a_src = pf + (size_t)(m0 + sr) * 512 + sk;
    const float* b_src[2];
    int wbB0[2], wbB1[2];
#pragma unroll
    for (int pass = 0; pass < 2; ++pass) {
        int c = c0 + pass * 64 + sr;
        int d = c & 511;
        int koff = (c >> 9) * 512;
        b_src[pass] = W1 + (size_t)d * 1024 + koff + sk;
        int rb = pass * 64 + sr, s = rb & 7;
        wbB0[pass] = rb * 128 + (((g0    ) ^ s) << 4);
        wbB1[pass] = rb * 128 + (((g0 + 1) ^ s) << 4);
    }
    const int sA = sr & 7;
    const int wbA0 = sr * 128 + (((g0    ) ^ sA) << 4);
    const int wbA1 = sr * 128 + (((g0 + 1) ^ sA) << 4);

    for (int kt = 0; kt < 512; kt += 64) {
        {
            const float* gp = a_src + kt;
            f32x4 x0 = ((const f32x4*)gp)[0];
            f32x4 x1 = ((const f32x4*)gp)[1];
            f32x4 x2 = ((const f32x4*)gp)[2];
            f32x4 x3 = ((const f32x4*)gp)[3];
            u32x4 P0, P1;
            P0[0] = cvt2_bf16(x0[0], x0[1]); P0[1] = cvt2_bf16(x0[2], x0[3]);
            P0[2] = cvt2_bf16(x1[0], x1[1]); P0[3] = cvt2_bf16(x1[2], x1[3]);
            P1[0] = cvt2_bf16(x2[0], x2[1]); P1[1] = cvt2_bf16(x2[2], x2[3]);
            P1[2] = cvt2_bf16(x3[0], x3[1]); P1[3] = cvt2_bf16(x3[2], x3[3]);
            *(u32x4*)((char*)&As[0][0] + wbA0) = P0;
            *(u32x4*)((char*)&As[0][0] + wbA1) = P1;
        }
#pragma unroll
        for (int pass = 0; pass < 2; ++pass) {
            const float* gp = b_src[pass] + kt;
            f32x4 x0 = ((const f32x4*)gp)[0];
            f32x4 x1 = ((const f32x4*)gp)[1];
            f32x4 x2 = ((const f32x4*)gp)[2];
            f32x4 x3 = ((const f32x4*)gp)[3];
            u32x4 P0, P1;
            P0[0] = cvt2_bf16(x0[0], x0[1]); P0[1] = cvt2_bf16(x0[2], x0[3]);
            P0[2] = cvt2_bf16(x1[0], x1[1]); P0[3] = cvt2_bf16(x1[2], x1[3]);
            P1[0] = cvt2_bf16(x2[0], x2[1]); P1[1] = cvt2_bf16(x2[2], x2[3]);
            P1[2] = cvt2_bf16(x3[0], x3[1]); P1[3] = cvt2_bf16(x3[2], x3[3]);
            *(u32x4*)((char*)&Bs[0][0] + wbB0[pass]) = P0;
            *(u32x4*)((char*)&Bs[0][0] + wbB1[pass]) = P1;
        }
        __syncthreads();
#pragma unroll
        for (int kk = 0; kk < 2; ++kk) {
            const int co = (((kk << 2) + lkq) ^ s7) << 3;
            bf16x8 af[2], bfr[4];
#pragma unroll
            for (int m = 0; m < 2; ++m)
                af[m] = *(const bf16x8*)(&As[0][0] + (wr * 32 + m * 16 + lr) * 64 + co);
#pragma unroll
            for (int n = 0; n < 4; ++n)
                bfr[n] = *(const bf16x8*)(&Bs[0][0] + (wc * 64 + n * 16 + lr) * 64 + co);
#pragma unroll
            for (int m = 0; m < 2; ++m)
#pragma unroll
                for (int n = 0; n < 4; ++n)
                    acc[m][n] = __builtin_amdgcn_mfma_f32_16x16x32_bf16(
                        af[m], bfr[n], acc[m][n], 0, 0, 0);
        }
        __syncthreads();
    }

    const int cr = lane >> 4;
    const int cc = lane & 15;
#pragma unroll
    for (int m = 0; m < 2; ++m) {
#pragma unroll
        for (int n = 0; n < 4; ++n) {
            int c = c0 + wc * 64 + n * 16 + cc;
            float bias = (c < 512) ? b1[c] : 0.0f;
            int rowb = m0 + wr * 32 + m * 16 + cr * 4;
#pragma unroll
            for (int r_ = 0; r_ < 4; ++r_)
                UV[(size_t)(rowb + r_) * 1024 + c] = acc[m][n][r_] + bias;
        }
    }
}

// ---------------------------------------------------------------------------
// Kernel 2: out = relu(U[i]+V[j]) @ W2^T + b2.
// BM=128, BN=256, BK=32, 16 steps. 256 threads = 4 waves (2M x 2N),
// wave tile 64x128, acc 8n x 4m x 4 = 128 regs.
// LDS 48 KB (A dbuf 16 + B dbuf 32) -> 3 blocks/CU = 12 waves/CU: independent
// blocks overlap each other's LDS/MFMA/L2 phases (m114 mechanism).
// Simple 2-phase loop: STAGE(n+1) issue -> MFMA(n) -> A-build(n+1) -> sync.
// Grid 992 = 8 XCD x 62 m-tiles x 2 col-halves (UV slice L2-resident/XCD).
// ---------------------------------------------------------------------------
__global__ __launch_bounds__(256, 3) void fused_gemm(const float* __restrict__ UV,
                                                     const unsigned short* __restrict__ W2r,
                                                     const float* __restrict__ b2,
                                                     float* __restrict__ out) {
    __shared__ unsigned char As[2][8192];     // 8 m-frags, frag-major (1 KB/frag)
    __shared__ unsigned char Bs[2][16384];    // 16 n-frags, frag-major

    const int t = threadIdx.x;
    const int bx = blockIdx.x;
    const int idx = bx >> 3;                       // 0..123 within XCD
    const int mt = (bx & 7) * 62 + (idx >> 1);     // 0..495
    const int ch = idx & 1;                        // col-half
    const int m0 = mt << 7;
    const int c0 = ch << 8;

    const int wave = t >> 6, lane = t & 63;
    const int wr = wave >> 1;        // 0..1  (M group, 64 rows)
    const int wc = wave & 1;         // 0..1  (N group, 128 cols)

    // ---- A-build mapping: thread -> (pair row, k-half of 16 floats)
    const int arow = t >> 1;         // 0..127
    const int ks = t & 1;            // k-half (16 floats)
    const float* uptr;
    const float* vptr;
    {
        int m = m0 + arow;
        int b = m / 992, p = m - b * 992;
        int i = p / 31, r = p - i * 31;
        int j = r + (r >= i ? 1 : 0);
        uptr = UV + (size_t)(b * 32 + i) * 1024 + ks * 16;
        vptr = UV + (size_t)(b * 32 + j) * 1024 + 512 + ks * 16;
    }
    // frag-major write offsets: frag = arow>>4; slot = (arow&15) + kslice*16
    const int wb0 = (arow >> 4) * 1024 + (arow & 15) * 16 + ks * 512;  // qq=0
    // qq=1 at wb0 + 256

    const int cr = lane >> 4;
    const int cc = lane & 15;

    f32x4 acc[8][4] = {};            // 8 N-frags x 4 M-frags

    // ---- A-build helper (16 floats -> 2 frag-major 16B writes)
#define BUILD_A(dst, U0, U1, U2, U3, V0, V1, V2, V3)                          \
    {                                                                          \
        f32x4 h0, h1, h2, h3;                                                  \
        _Pragma("unroll")                                                      \
        for (int q = 0; q < 4; ++q) {                                          \
            h0[q] = fmaxf(U0[q] + V0[q], 0.0f);                                \
            h1[q] = fmaxf(U1[q] + V1[q], 0.0f);                                \
            h2[q] = fmaxf(U2[q] + V2[q], 0.0f);                                \
            h3[q] = fmaxf(U3[q] + V3[q], 0.0f);                                \
        }                                                                      \
        u32x4 P0, P1;                                                          \
        P0[0] = cvt2_bf16(h0[0], h0[1]); P0[1] = cvt2_bf16(h0[2], h0[3]);      \
        P0[2] = cvt2_bf16(h1[0], h1[1]); P0[3] = cvt2_bf16(h1[2], h1[3]);      \
        P1[0] = cvt2_bf16(h2[0], h2[1]); P1[1] = cvt2_bf16(h2[2], h2[3]);      \
        P1[2] = cvt2_bf16(h3[0], h3[1]); P1[3] = cvt2_bf16(h3[2], h3[3]);      \
        *(u32x4*)((dst) + wb0) = P0;                                           \
        *(u32x4*)((dst) + wb0 + 256) = P1;                                     \
    }

    // ---- prologue: UV(0), DMA B(0) -> Bs[0], build A(0) -> As[0]
    {
        f32x4 u0 = ((const f32x4*)uptr)[0], u1 = ((const f32x4*)uptr)[1];
        f32x4 u2 = ((const f32x4*)uptr)[2], u3 = ((const f32x4*)uptr)[3];
        f32x4 v0 = ((const f32x4*)vptr)[0], v1 = ((const f32x4*)vptr)[1];
        f32x4 v2 = ((const f32x4*)vptr)[2], v3 = ((const f32x4*)vptr)[3];
        const char* gs = (const char*)W2r + (size_t)ch * 16384 + t * 16;
#pragma unroll
        for (int q = 0; q < 4; ++q)
            async_lds16(gs + q * 4096, &Bs[0][0] + q * 4096 + wave * 1024);
        BUILD_A(&As[0][0], u0, u1, u2, u3, v0, v1, v2, v3);
    }
    __syncthreads();

#pragma unroll 1
    for (int step = 0; step < 16; ++step) {
        const int buf = step & 1;

        // ---- STAGE(step+1): issue UV loads + B DMA first (overlap MFMA)
        f32x4 u0, u1, u2, u3, v0, v1, v2, v3;
        if (step < 15) {
            const float* up = uptr + (step + 1) * 32;
            const float* vp = vptr + (step + 1) * 32;
            u0 = ((const f32x4*)up)[0]; u1 = ((const f32x4*)up)[1];
            u2 = ((const f32x4*)up)[2]; u3 = ((const f32x4*)up)[3];
            v0 = ((const f32x4*)vp)[0]; v1 = ((const f32x4*)vp)[1];
            v2 = ((const f32x4*)vp)[2]; v3 = ((const f32x4*)vp)[3];
            const char* gs = (const char*)W2r +
                             (size_t)((step + 1) * 2 + ch) * 16384 + t * 16;
#pragma unroll
            for (int q = 0; q < 4; ++q)
                async_lds16(gs + q * 4096, &Bs[buf ^ 1][0] + q * 4096 + wave * 1024);
        }

        // ---- MFMA on As[buf]/Bs[buf] (frag-major, lane-linear, conflict-free)
        {
            const unsigned char* aB = &As[buf][0];
            const unsigned char* bB = &Bs[buf][0];
            bf16x8 af[4], bfr[8];
#pragma unroll
            for (int m = 0; m < 4; ++m)
                af[m] = *(const bf16x8*)(aB + (wr * 4 + m) * 1024 + lane * 16);
#pragma unroll
            for (int n = 0; n < 8; ++n)
                bfr[n] = *(const bf16x8*)(bB + (wc * 8 + n) * 1024 + lane * 16);
            __builtin_amdgcn_s_setprio(1);
#pragma unroll
            for (int n = 0; n < 8; ++n)
#pragma unroll
                for (int m = 0; m < 4; ++m)
                    acc[n][m] = __builtin_amdgcn_mfma_f32_16x16x32_bf16(
                        af[m], bfr[n], acc[n][m], 0, 0, 0);
            __builtin_amdgcn_s_setprio(0);
        }

        // ---- finish A(step+1)
        if (step < 15) {
            BUILD_A(&As[buf ^ 1][0], u0, u1, u2, u3, v0, v1, v2, v3);
        }
        __syncthreads();
    }
#undef BUILD_A

    // ---- epilogue: C/D layout col=lane&15, row=(lane>>4)*4+reg
#pragma unroll
    for (int n = 0; n < 8; ++n) {
        int col = c0 + wc * 128 + n * 16 + cc;
        float bias = b2[col];
#pragma unroll
        for (int m = 0; m < 4; ++m) {
            int rowb = m0 + wr * 64 + m * 16 + cr * 4;
#pragma unroll
            for (int r_ = 0; r_ < 4; ++r_)
                out[(size_t)(rowb + r_) * 512 + col] = acc[n][m][r_] + bias;
        }
    }
}

// ---------------------------------------------------------------------------
extern "C" void kernel_launch(void* const* d_in, const int* in_sizes, int n_in,
                              void* d_out, int out_size, void* d_ws, size_t ws_size,
                              hipStream_t stream) {
    const float* pf = (const float*)d_in[0];   // (64, 32, 512)
    const float* W1 = (const float*)d_in[1];   // (512, 1024)
    const float* b1 = (const float*)d_in[2];   // (512,)
    const float* W2 = (const float*)d_in[3];   // (512, 512)
    const float* b2 = (const float*)d_in[4];   // (512,)
    float* out = (float*)d_out;                // (64, 992, 512)

    float* UV = (float*)d_ws;                                       // 8 MB
    unsigned short* W2r = (unsigned short*)((char*)d_ws + (size_t)8 * 1024 * 1024); // 512 KB

    prep<<<dim3(384), dim3(256), 0, stream>>>(pf, W1, b1, W2, UV, W2r);
    fused_gemm<<<dim3(992), dim3(256), 0, stream>>>(UV, W2r, b2, out);
}

// Round 8
// 80.404 us; speedup vs baseline: 3.3423x; 3.3423x over previous
//
#include <hip/hip_runtime.h>
#include <hip/hip_bf16.h>
#include <stdint.h>

// Problem: B=64, N=32, D=512, P=992 pairs, M = B*P = 63488.
// out[m,d] = relu(U[i(m)] + V[j(m)])·W2[d,:] + b2[d]
// U = pf @ W1[:,:512]^T (+b1), V = pf @ W1[:,512:]^T   (only 2048 distinct rows)

typedef __attribute__((ext_vector_type(4))) float f32x4;
typedef __attribute__((ext_vector_type(8))) short bf16x8;
typedef __attribute__((ext_vector_type(4))) unsigned int u32x4;
typedef __attribute__((ext_vector_type(2))) unsigned int u32x2;

__device__ __forceinline__ uint32_t cvt2_bf16(float a, float b) {
    __hip_bfloat162 h = __float22bfloat162_rn(make_float2(a, b));
    uint32_t u;
    __builtin_memcpy(&u, &h, 4);
    return u;
}

__device__ __forceinline__ void async_lds16(const void* g, void* l) {
    __builtin_amdgcn_global_load_lds(
        (const __attribute__((address_space(1))) void*)g,
        (__attribute__((address_space(3))) void*)l, 16, 0, 0);
}

// ---------------------------------------------------------------------------
// Kernel 1 (merged): blocks 0..255 -> uv_gemm tile; blocks 256..383 ->
// W2 rearrange into MFMA-fragment order (32768 16B slots):
//   slot s: l = s&63, fn = (s>>6)&31, kt = s>>11
//   col = fn*16 + (l&15), k = kt*32 + (l>>4)*8
// -> chunk kt is a contiguous 32 KB block (the per-step DMA unit).
// ---------------------------------------------------------------------------
__global__ __launch_bounds__(256) void prep(const float* __restrict__ pf,
                                            const float* __restrict__ W1,
                                            const float* __restrict__ b1,
                                            const float* __restrict__ W2,
                                            float* __restrict__ UV,
                                            unsigned short* __restrict__ W2r) {
    __shared__ unsigned short As[64][64];
    __shared__ unsigned short Bs[128][64];

    const int t = threadIdx.x;
    const int bxg = blockIdx.x;

    if (bxg >= 256) {
        int s = (bxg - 256) * 256 + t;           // 0..32767
        int l = s & 63;
        int fn = (s >> 6) & 31;
        int kt = s >> 11;
        int col = fn * 16 + (l & 15);
        int k = kt * 32 + (l >> 4) * 8;
        const float* src = W2 + (size_t)col * 512 + k;
        f32x4 a = ((const f32x4*)src)[0];
        f32x4 b = ((const f32x4*)src)[1];
        u32x4 P;
        P[0] = cvt2_bf16(a[0], a[1]); P[1] = cvt2_bf16(a[2], a[3]);
        P[2] = cvt2_bf16(b[0], b[1]); P[3] = cvt2_bf16(b[2], b[3]);
        *(u32x4*)(W2r + (size_t)s * 8) = P;
        return;
    }

    // ---- uv_gemm: 64x128 tile, BK=64, 4 waves, XOR-swizzled LDS
    const int m0 = (bxg >> 3) * 64;
    const int c0 = (bxg & 7) * 128;

    const int sr = t >> 2;
    const int sk = (t & 3) << 4;
    const int g0 = (t & 3) << 1;

    const int wave = t >> 6, lane = t & 63;
    const int wr = wave >> 1, wc = wave & 1;
    const int lr = lane & 15, lkq = lane >> 4;
    const int s7 = lr & 7;

    f32x4 acc[2][4] = {};

    const float* a_src = pf + (size_t)(m0 + sr) * 512 + sk;
    const float* b_src[2];
    int wbB0[2], wbB1[2];
#pragma unroll
    for (int pass = 0; pass < 2; ++pass) {
        int c = c0 + pass * 64 + sr;
        int d = c & 511;
        int koff = (c >> 9) * 512;
        b_src[pass] = W1 + (size_t)d * 1024 + koff + sk;
        int rb = pass * 64 + sr, s = rb & 7;
        wbB0[pass] = rb * 128 + (((g0    ) ^ s) << 4);
        wbB1[pass] = rb * 128 + (((g0 + 1) ^ s) << 4);
    }
    const int sA = sr & 7;
    const int wbA0 = sr * 128 + (((g0    ) ^ sA) << 4);
    const int wbA1 = sr * 128 + (((g0 + 1) ^ sA) << 4);

    for (int kt = 0; kt < 512; kt += 64) {
        {
            const float* gp = a_src + kt;
            f32x4 x0 = ((const f32x4*)gp)[0];
            f32x4 x1 = ((const f32x4*)gp)[1];
            f32x4 x2 = ((const f32x4*)gp)[2];
            f32x4 x3 = ((const f32x4*)gp)[3];
            u32x4 P0, P1;
            P0[0] = cvt2_bf16(x0[0], x0[1]); P0[1] = cvt2_bf16(x0[2], x0[3]);
            P0[2] = cvt2_bf16(x1[0], x1[1]); P0[3] = cvt2_bf16(x1[2], x1[3]);
            P1[0] = cvt2_bf16(x2[0], x2[1]); P1[1] = cvt2_bf16(x2[2], x2[3]);
            P1[2] = cvt2_bf16(x3[0], x3[1]); P1[3] = cvt2_bf16(x3[2], x3[3]);
            *(u32x4*)((char*)&As[0][0] + wbA0) = P0;
            *(u32x4*)((char*)&As[0][0] + wbA1) = P1;
        }
#pragma unroll
        for (int pass = 0; pass < 2; ++pass) {
            const float* gp = b_src[pass] + kt;
            f32x4 x0 = ((const f32x4*)gp)[0];
            f32x4 x1 = ((const f32x4*)gp)[1];
            f32x4 x2 = ((const f32x4*)gp)[2];
            f32x4 x3 = ((const f32x4*)gp)[3];
            u32x4 P0, P1;
            P0[0] = cvt2_bf16(x0[0], x0[1]); P0[1] = cvt2_bf16(x0[2], x0[3]);
            P0[2] = cvt2_bf16(x1[0], x1[1]); P0[3] = cvt2_bf16(x1[2], x1[3]);
            P1[0] = cvt2_bf16(x2[0], x2[1]); P1[1] = cvt2_bf16(x2[2], x2[3]);
            P1[2] = cvt2_bf16(x3[0], x3[1]); P1[3] = cvt2_bf16(x3[2], x3[3]);
            *(u32x4*)((char*)&Bs[0][0] + wbB0[pass]) = P0;
            *(u32x4*)((char*)&Bs[0][0] + wbB1[pass]) = P1;
        }
        __syncthreads();
#pragma unroll
        for (int kk = 0; kk < 2; ++kk) {
            const int co = (((kk << 2) + lkq) ^ s7) << 3;
            bf16x8 af[2], bfr[4];
#pragma unroll
            for (int m = 0; m < 2; ++m)
                af[m] = *(const bf16x8*)(&As[0][0] + (wr * 32 + m * 16 + lr) * 64 + co);
#pragma unroll
            for (int n = 0; n < 4; ++n)
                bfr[n] = *(const bf16x8*)(&Bs[0][0] + (wc * 64 + n * 16 + lr) * 64 + co);
#pragma unroll
            for (int m = 0; m < 2; ++m)
#pragma unroll
                for (int n = 0; n < 4; ++n)
                    acc[m][n] = __builtin_amdgcn_mfma_f32_16x16x32_bf16(
                        af[m], bfr[n], acc[m][n], 0, 0, 0);
        }
        __syncthreads();
    }

    const int cr = lane >> 4;
    const int cc = lane & 15;
#pragma unroll
    for (int m = 0; m < 2; ++m) {
#pragma unroll
        for (int n = 0; n < 4; ++n) {
            int c = c0 + wc * 64 + n * 16 + cc;
            float bias = (c < 512) ? b1[c] : 0.0f;
            int rowb = m0 + wr * 32 + m * 16 + cr * 4;
#pragma unroll
            for (int r_ = 0; r_ < 4; ++r_)
                UV[(size_t)(rowb + r_) * 1024 + c] = acc[m][n][r_] + bias;
        }
    }
}

// ---------------------------------------------------------------------------
// Kernel 2: out = relu(U[i]+V[j]) @ W2^T + b2.
// BM=64, BN=512 (FULL width -- R7 lesson: col-split destroys L2 residency),
// BK=32, 16 steps. 256 threads = 4 waves, wave tile 64x128, acc 128 regs.
// LDS 72 KB (A dbuf 8 + B dbuf 64) -> 2 independent blocks/CU (the VGPR cap
// of 2 waves/SIMD now holds TWO 4-wave blocks instead of one 8-wave block);
// cross-block phase overlap is the m114/m97 pipelining mechanism.
// One __syncthreads per step: its vmcnt(0) lands on a DMA issued a full
// step earlier (R5-proven ordering).
// Grid 992 = 8 XCD x 124 m-tiles; per-XCD UV slice 1 MB (L2-resident).
// ---------------------------------------------------------------------------
__global__ __launch_bounds__(256, 2) void fused_gemm(const float* __restrict__ UV,
                                                     const unsigned short* __restrict__ W2r,
                                                     const float* __restrict__ b2,
                                                     float* __restrict__ out) {
    __shared__ unsigned char As[2][4096];     // 4 m-frags, frag-major (1 KB/frag)
    __shared__ unsigned char Bs[2][32768];    // 32 n-frags, frag-major

    const int t = threadIdx.x;
    const int bx = blockIdx.x;
    const int mt = (bx & 7) * 124 + (bx >> 3);   // XCD-chunked, bijective (992=8*124)
    const int m0 = mt << 6;

    const int wave = t >> 6, lane = t & 63;      // wave = N group (128 cols)

    // ---- A-build mapping: thread -> (pair row, 8-float k-slice)
    const int arow = t >> 2;         // 0..63
    const int ks = t & 3;            // k-slice
    const float* uptr;
    const float* vptr;
    {
        int m = m0 + arow;
        int b = m / 992, p = m - b * 992;
        int i = p / 31, r = p - i * 31;
        int j = r + (r >= i ? 1 : 0);
        uptr = UV + (size_t)(b * 32 + i) * 1024 + ks * 8;
        vptr = UV + (size_t)(b * 32 + j) * 1024 + 512 + ks * 8;
    }
    // frag-major write: frag = arow>>4, lane = ks*16 + (arow&15)
    const int awoff = (arow >> 4) * 1024 + (ks * 16 + (arow & 15)) * 16;

    const int cr = lane >> 4;
    const int cc = lane & 15;

    f32x4 acc[8][4] = {};            // 8 N-frags x 4 M-frags

#define BUILD_A(dst, U0, U1, V0, V1)                                           \
    {                                                                          \
        f32x4 h0, h1;                                                          \
        _Pragma("unroll")                                                      \
        for (int q = 0; q < 4; ++q) {                                          \
            h0[q] = fmaxf(U0[q] + V0[q], 0.0f);                                \
            h1[q] = fmaxf(U1[q] + V1[q], 0.0f);                                \
        }                                                                      \
        u32x4 P;                                                               \
        P[0] = cvt2_bf16(h0[0], h0[1]); P[1] = cvt2_bf16(h0[2], h0[3]);        \
        P[2] = cvt2_bf16(h1[0], h1[1]); P[3] = cvt2_bf16(h1[2], h1[3]);        \
        *(u32x4*)((dst) + awoff) = P;                                          \
    }

    // ---- prologue: UV(0), DMA B(0) -> Bs[0], build A(0) -> As[0]
    {
        f32x4 u0 = ((const f32x4*)uptr)[0], u1 = ((const f32x4*)uptr)[1];
        f32x4 v0 = ((const f32x4*)vptr)[0], v1 = ((const f32x4*)vptr)[1];
        const char* gs = (const char*)W2r + t * 16;
#pragma unroll
        for (int q = 0; q < 8; ++q)
            async_lds16(gs + q * 4096, &Bs[0][0] + q * 4096 + wave * 1024);
        BUILD_A(&As[0][0], u0, u1, v0, v1);
    }

#pragma unroll 1
    for (int step = 0; step < 16; ++step) {
        const int buf = step & 1;
        // vmcnt(0)+lgkmcnt(0)+barrier: DMA B(step) was issued a full step ago;
        // A(step) ds_writes drained; everyone done reading buf^1.
        __syncthreads();

        // ---- issue next-step loads into buf^1; they ride through this step
        f32x4 u0, u1, v0, v1;
        if (step < 15) {
            const float* up = uptr + (step + 1) * 32;
            const float* vp = vptr + (step + 1) * 32;
            u0 = ((const f32x4*)up)[0]; u1 = ((const f32x4*)up)[1];
            v0 = ((const f32x4*)vp)[0]; v1 = ((const f32x4*)vp)[1];
            const char* gs = (const char*)W2r + (step + 1) * 32768 + t * 16;
#pragma unroll
            for (int q = 0; q < 8; ++q)
                async_lds16(gs + q * 4096, &Bs[buf ^ 1][0] + q * 4096 + wave * 1024);
        }

        // ---- MFMA on As[buf]/Bs[buf] (frag-major, lane-linear, conflict-free)
        {
            const unsigned char* aB = &As[buf][0];
            const unsigned char* bB = &Bs[buf][0];
            bf16x8 af[4], bfr[8];
#pragma unroll
            for (int m = 0; m < 4; ++m)
                af[m] = *(const bf16x8*)(aB + m * 1024 + lane * 16);
#pragma unroll
            for (int n = 0; n < 8; ++n)
                bfr[n] = *(const bf16x8*)(bB + (wave * 8 + n) * 1024 + lane * 16);
            __builtin_amdgcn_s_setprio(1);
#pragma unroll
            for (int n = 0; n < 8; ++n)
#pragma unroll
                for (int m = 0; m < 4; ++m)
                    acc[n][m] = __builtin_amdgcn_mfma_f32_16x16x32_bf16(
                        af[m], bfr[n], acc[n][m], 0, 0, 0);
            __builtin_amdgcn_s_setprio(0);
        }

        // ---- finish A(step+1): relu/cvt -> frag-major ds_write into buf^1
        if (step < 15) {
            BUILD_A(&As[buf ^ 1][0], u0, u1, v0, v1);
        }
    }
#undef BUILD_A

    // ---- epilogue: C/D layout col=lane&15, row=(lane>>4)*4+reg
#pragma unroll
    for (int n = 0; n < 8; ++n) {
        int col = wave * 128 + n * 16 + cc;
        float bias = b2[col];
#pragma unroll
        for (int m = 0; m < 4; ++m) {
            int rowb = m0 + m * 16 + cr * 4;
#pragma unroll
            for (int r_ = 0; r_ < 4; ++r_)
                out[(size_t)(rowb + r_) * 512 + col] = acc[n][m][r_] + bias;
        }
    }
}

// ---------------------------------------------------------------------------
extern "C" void kernel_launch(void* const* d_in, const int* in_sizes, int n_in,
                              void* d_out, int out_size, void* d_ws, size_t ws_size,
                              hipStream_t stream) {
    const float* pf = (const float*)d_in[0];   // (64, 32, 512)
    const float* W1 = (const float*)d_in[1];   // (512, 1024)
    const float* b1 = (const float*)d_in[2];   // (512,)
    const float* W2 = (const float*)d_in[3];   // (512, 512)
    const float* b2 = (const float*)d_in[4];   // (512,)
    float* out = (float*)d_out;                // (64, 992, 512)

    float* UV = (float*)d_ws;                                       // 8 MB
    unsigned short* W2r = (unsigned short*)((char*)d_ws + (size_t)8 * 1024 * 1024); // 512 KB

    prep<<<dim3(384), dim3(256), 0, stream>>>(pf, W1, b1, W2, UV, W2r);
    fused_gemm<<<dim3(992), dim3(256), 0, stream>>>(UV, W2r, b2, out);
}

// Round 10
// 78.957 us; speedup vs baseline: 3.4035x; 1.0183x over previous
//
#include <hip/hip_runtime.h>
#include <hip/hip_bf16.h>
#include <stdint.h>

// Problem: B=64, N=32, D=512, P=992 pairs, M = B*P = 63488.
// out[m,d] = relu(U[i(m)] + V[j(m)])·W2[d,:] + b2[d]
// U = pf @ W1[:,:512]^T (+b1), V = pf @ W1[:,512:]^T   (only 2048 distinct rows)
//
// Config ledger: acc=128 regs -> 2 waves/SIMD hard cap -> 8 waves/CU.
//   R7 lesson: BN<512 (col-split) caused catastrophic L2 thrash. Keep BN=512.
//   R8 lesson: 2x4-wave blocks/CU beats 1x8-wave block (76-87 -> ~60-65 us).
//   R9 lesson: ping-pong reload guards must cover the LAST consumer
//   (Q feeds BUILD_A at s2+2; guard is s2<14, not s2<12).

typedef __attribute__((ext_vector_type(4))) float f32x4;
typedef __attribute__((ext_vector_type(8))) short bf16x8;
typedef __attribute__((ext_vector_type(4))) unsigned int u32x4;

__device__ __forceinline__ uint32_t cvt2_bf16(float a, float b) {
    __hip_bfloat162 h = __float22bfloat162_rn(make_float2(a, b));
    uint32_t u;
    __builtin_memcpy(&u, &h, 4);
    return u;
}

__device__ __forceinline__ void async_lds16(const void* g, void* l) {
    __builtin_amdgcn_global_load_lds(
        (const __attribute__((address_space(1))) void*)g,
        (__attribute__((address_space(3))) void*)l, 16, 0, 0);
}

// ---------------------------------------------------------------------------
// Kernel 1 (merged): blocks 0..511 -> uv_gemm 32x128 tiles (2.5 blocks/CU);
// blocks 512..639 -> W2 rearrange into MFMA-fragment order (32768 16B slots).
// ---------------------------------------------------------------------------
__global__ __launch_bounds__(256) void prep(const float* __restrict__ pf,
                                            const float* __restrict__ W1,
                                            const float* __restrict__ b1,
                                            const float* __restrict__ W2,
                                            float* __restrict__ UV,
                                            unsigned short* __restrict__ W2r) {
    __shared__ unsigned short As[32][64];
    __shared__ unsigned short Bs[128][64];

    const int t = threadIdx.x;
    const int bxg = blockIdx.x;

    if (bxg >= 512) {
        // ---- W2 rearrange: slot s = [kt(16)][fn(32)][l(64)]
        int s = (bxg - 512) * 256 + t;           // 0..32767
        int l = s & 63;
        int fn = (s >> 6) & 31;
        int kt = s >> 11;
        int col = fn * 16 + (l & 15);
        int k = kt * 32 + (l >> 4) * 8;
        const float* src = W2 + (size_t)col * 512 + k;
        f32x4 a = ((const f32x4*)src)[0];
        f32x4 b = ((const f32x4*)src)[1];
        u32x4 P;
        P[0] = cvt2_bf16(a[0], a[1]); P[1] = cvt2_bf16(a[2], a[3]);
        P[2] = cvt2_bf16(b[0], b[1]); P[3] = cvt2_bf16(b[2], b[3]);
        *(u32x4*)(W2r + (size_t)s * 8) = P;
        return;
    }

    // ---- uv_gemm: 32x128 tile, BK=64, 4 waves (2M x 2N), XOR-swizzled LDS
    const int m0 = (bxg >> 3) * 32;              // 64 m-tiles
    const int c0 = (bxg & 7) * 128;              // 8 col tiles

    const int row8 = t >> 3;                     // 0..31 (A row / B row-in-pass)
    const int g = t & 7;                         // 16B granule (8 floats)

    const int wave = t >> 6, lane = t & 63;
    const int wr = wave >> 1, wc = wave & 1;
    const int lr = lane & 15, lkq = lane >> 4;
    const int s7 = lr & 7;

    f32x4 acc[4] = {};                           // 1 m-frag x 4 n-frags

    const float* a_src = pf + (size_t)(m0 + row8) * 512 + g * 8;
    const float* b_src[4];
    int wbB[4];
#pragma unroll
    for (int p = 0; p < 4; ++p) {
        int rb = p * 32 + row8;
        int c = c0 + rb;
        int d = c & 511;
        int koff = (c >> 9) * 512;
        b_src[p] = W1 + (size_t)d * 1024 + koff + g * 8;
        wbB[p] = rb * 128 + ((g ^ (rb & 7)) << 4);
    }
    const int wbA = row8 * 128 + ((g ^ (row8 & 7)) << 4);

    for (int kt = 0; kt < 512; kt += 64) {
        {
            const float* gp = a_src + kt;
            f32x4 x0 = ((const f32x4*)gp)[0];
            f32x4 x1 = ((const f32x4*)gp)[1];
            u32x4 P;
            P[0] = cvt2_bf16(x0[0], x0[1]); P[1] = cvt2_bf16(x0[2], x0[3]);
            P[2] = cvt2_bf16(x1[0], x1[1]); P[3] = cvt2_bf16(x1[2], x1[3]);
            *(u32x4*)((char*)&As[0][0] + wbA) = P;
        }
#pragma unroll
        for (int p = 0; p < 4; ++p) {
            const float* gp = b_src[p] + kt;
            f32x4 x0 = ((const f32x4*)gp)[0];
            f32x4 x1 = ((const f32x4*)gp)[1];
            u32x4 P;
            P[0] = cvt2_bf16(x0[0], x0[1]); P[1] = cvt2_bf16(x0[2], x0[3]);
            P[2] = cvt2_bf16(x1[0], x1[1]); P[3] = cvt2_bf16(x1[2], x1[3]);
            *(u32x4*)((char*)&Bs[0][0] + wbB[p]) = P;
        }
        __syncthreads();
#pragma unroll
        for (int kk = 0; kk < 2; ++kk) {
            const int co = (((kk << 2) + lkq) ^ s7) << 3;    // ushort offset
            bf16x8 af = *(const bf16x8*)(&As[0][0] + (wr * 16 + lr) * 64 + co);
#pragma unroll
            for (int n = 0; n < 4; ++n) {
                bf16x8 bfr = *(const bf16x8*)(&Bs[0][0] + (wc * 64 + n * 16 + lr) * 64 + co);
                acc[n] = __builtin_amdgcn_mfma_f32_16x16x32_bf16(af, bfr, acc[n], 0, 0, 0);
            }
        }
        __syncthreads();
    }

    const int cr = lane >> 4;
    const int cc = lane & 15;
#pragma unroll
    for (int n = 0; n < 4; ++n) {
        int c = c0 + wc * 64 + n * 16 + cc;
        float bias = (c < 512) ? b1[c] : 0.0f;
        int rowb = m0 + wr * 16 + cr * 4;
#pragma unroll
        for (int r_ = 0; r_ < 4; ++r_)
            UV[(size_t)(rowb + r_) * 1024 + c] = acc[n][r_] + bias;
    }
}

// ---------------------------------------------------------------------------
// Kernel 2: out = relu(U[i]+V[j]) @ W2^T + b2.
// BM=64, BN=512, BK=32, 16 steps. 256 thr = 4 waves, wave tile 64x128.
// LDS 72 KB -> 2 blocks/CU; frag-major (conflict-free). UV prefetch DEPTH 2
// (ping-pong P/Q regs, static unroll x2): BUILD_A consumes regs loaded a full
// step earlier -> no consume stall; barrier vmcnt(0) drains only the DMA
// issued one step earlier. Grid 992 = 8 XCD x 124 m-tiles (UV L2-resident).
// ---------------------------------------------------------------------------
__global__ __launch_bounds__(256, 2) void fused_gemm(const float* __restrict__ UV,
                                                     const unsigned short* __restrict__ W2r,
                                                     const float* __restrict__ b2,
                                                     float* __restrict__ out) {
    __shared__ unsigned char As[2][4096];     // 4 m-frags, frag-major (1 KB/frag)
    __shared__ unsigned char Bs[2][32768];    // 32 n-frags, frag-major

    const int t = threadIdx.x;
    const int bx = blockIdx.x;
    const int mt = (bx & 7) * 124 + (bx >> 3);   // XCD-chunked, bijective (992=8*124)
    const int m0 = mt << 6;

    const int wave = t >> 6, lane = t & 63;      // wave = N group (128 cols)

    // ---- A-build mapping: thread -> (pair row, 8-float k-slice)
    const int arow = t >> 2;         // 0..63
    const int ks = t & 3;            // k-slice
    const float* uptr;
    const float* vptr;
    {
        int m = m0 + arow;
        int b = m / 992, p = m - b * 992;
        int i = p / 31, r = p - i * 31;
        int j = r + (r >= i ? 1 : 0);
        uptr = UV + (size_t)(b * 32 + i) * 1024 + ks * 8;
        vptr = UV + (size_t)(b * 32 + j) * 1024 + 512 + ks * 8;
    }
    // frag-major write: frag = arow>>4, lane = ks*16 + (arow&15)
    const int awoff = (arow >> 4) * 1024 + (ks * 16 + (arow & 15)) * 16;

    const int cr = lane >> 4;
    const int cc = lane & 15;

    f32x4 acc[8][4] = {};            // 8 N-frags x 4 M-frags

    f32x4 Pu0, Pu1, Pv0, Pv1;        // ping
    f32x4 Qu0, Qu1, Qv0, Qv1;        // pong

#define DMA_B(S, DSTBUF)                                                       \
    {                                                                          \
        const char* gs = (const char*)W2r + (S) * 32768 + t * 16;              \
        _Pragma("unroll")                                                      \
        for (int q = 0; q < 8; ++q)                                            \
            async_lds16(gs + q * 4096, &Bs[DSTBUF][0] + q * 4096 + wave * 1024);\
    }

#define LOAD_UV(S, U0, U1, V0, V1)                                             \
    {                                                                          \
        const float* up = uptr + (S) * 32;                                     \
        const float* vp = vptr + (S) * 32;                                     \
        U0 = ((const f32x4*)up)[0]; U1 = ((const f32x4*)up)[1];                \
        V0 = ((const f32x4*)vp)[0]; V1 = ((const f32x4*)vp)[1];                \
    }

#define BUILD_A(DSTBUF, U0, U1, V0, V1)                                        \
    {                                                                          \
        f32x4 h0, h1;                                                          \
        _Pragma("unroll")                                                      \
        for (int q = 0; q < 4; ++q) {                                          \
            h0[q] = fmaxf(U0[q] + V0[q], 0.0f);                                \
            h1[q] = fmaxf(U1[q] + V1[q], 0.0f);                                \
        }                                                                      \
        u32x4 P;                                                               \
        P[0] = cvt2_bf16(h0[0], h0[1]); P[1] = cvt2_bf16(h0[2], h0[3]);        \
        P[2] = cvt2_bf16(h1[0], h1[1]); P[3] = cvt2_bf16(h1[2], h1[3]);        \
        *(u32x4*)(&As[DSTBUF][0] + awoff) = P;                                 \
    }

#define MFMA_STEP(BUF)                                                         \
    {                                                                          \
        const unsigned char* aB = &As[BUF][0];                                 \
        const unsigned char* bB = &Bs[BUF][0];                                 \
        bf16x8 af[4], bfr[8];                                                  \
        _Pragma("unroll")                                                      \
        for (int m = 0; m < 4; ++m)                                            \
            af[m] = *(const bf16x8*)(aB + m * 1024 + lane * 16);               \
        _Pragma("unroll")                                                      \
        for (int n = 0; n < 8; ++n)                                            \
            bfr[n] = *(const bf16x8*)(bB + (wave * 8 + n) * 1024 + lane * 16); \
        __builtin_amdgcn_s_setprio(1);                                         \
        _Pragma("unroll")                                                      \
        for (int n = 0; n < 8; ++n)                                            \
            _Pragma("unroll")                                                  \
            for (int m = 0; m < 4; ++m)                                        \
                acc[n][m] = __builtin_amdgcn_mfma_f32_16x16x32_bf16(           \
                    af[m], bfr[n], acc[n][m], 0, 0, 0);                        \
        __builtin_amdgcn_s_setprio(0);                                         \
    }

    // ---- prologue: DMA B(0); UV(0)->P; UV(1)->Q; build A(0) from P.
    DMA_B(0, 0);
    LOAD_UV(0, Pu0, Pu1, Pv0, Pv1);
    LOAD_UV(1, Qu0, Qu1, Qv0, Qv1);
    BUILD_A(0, Pu0, Pu1, Pv0, Pv1);

#pragma unroll 1
    for (int s2 = 0; s2 < 16; s2 += 2) {
        // ======== even step s = s2 (buf 0) ========
        // barrier drains: DMA(s2) [issued a full step ago] + UV regs [older].
        __syncthreads();
        DMA_B(s2 + 1, 1);                            // s2 <= 14 -> always valid
        if (s2 < 14) LOAD_UV(s2 + 2, Pu0, Pu1, Pv0, Pv1);   // P free (consumed)
        MFMA_STEP(0);
        BUILD_A(1, Qu0, Qu1, Qv0, Qv1);              // regs loaded last step

        // ======== odd step s = s2+1 (buf 1) ========
        __syncthreads();
        if (s2 < 14) DMA_B(s2 + 2, 0);
        if (s2 < 14) LOAD_UV(s2 + 3, Qu0, Qu1, Qv0, Qv1);   // R9 bug: was s2<12,
                                                            // starving UV(15)
        MFMA_STEP(1);
        if (s2 < 14) BUILD_A(0, Pu0, Pu1, Pv0, Pv1);
    }
#undef DMA_B
#undef LOAD_UV
#undef BUILD_A
#undef MFMA_STEP

    // ---- epilogue: C/D layout col=lane&15, row=(lane>>4)*4+reg
#pragma unroll
    for (int n = 0; n < 8; ++n) {
        int col = wave * 128 + n * 16 + cc;
        float bias = b2[col];
#pragma unroll
        for (int m = 0; m < 4; ++m) {
            int rowb = m0 + m * 16 + cr * 4;
#pragma unroll
            for (int r_ = 0; r_ < 4; ++r_)
                out[(size_t)(rowb + r_) * 512 + col] = acc[n][m][r_] + bias;
        }
    }
}

// ---------------------------------------------------------------------------
extern "C" void kernel_launch(void* const* d_in, const int* in_sizes, int n_in,
                              void* d_out, int out_size, void* d_ws, size_t ws_size,
                              hipStream_t stream) {
    const float* pf = (const float*)d_in[0];   // (64, 32, 512)
    const float* W1 = (const float*)d_in[1];   // (512, 1024)
    const float* b1 = (const float*)d_in[2];   // (512,)
    const float* W2 = (const float*)d_in[3];   // (512, 512)
    const float* b2 = (const float*)d_in[4];   // (512,)
    float* out = (float*)d_out;                // (64, 992, 512)

    float* UV = (float*)d_ws;                                       // 8 MB
    unsigned short* W2r = (unsigned short*)((char*)d_ws + (size_t)8 * 1024 * 1024); // 512 KB

    prep<<<dim3(640), dim3(256), 0, stream>>>(pf, W1, b1, W2, UV, W2r);
    fused_gemm<<<dim3(992), dim3(256), 0, stream>>>(UV, W2r, b2, out);
}